// Round 7
// baseline (122.937 us; speedup 1.0000x reference)
//
#include <hip/hip_runtime.h>
#include <math.h>

#define NMODES 6400
#define TB     320                // 5 waves
#define MPT    10                 // modes per thread
#define MG     2                  // mode groups: TB*MPT*MG == NMODES
#define BATCH  6                  // samples per pipelined batch
#define TC     54                 // samples per time-chunk (9 batches)

static __device__ __forceinline__ float softplusf(float x) {
    return log1pf(expf(-fabsf(x))) + fmaxf(x, 0.0f);
}
static __device__ __forceinline__ float sigmoidf(float x) {
    return 1.0f / (1.0f + expf(-x));
}

// ONE launch: 6400 threads compute per-mode constants; all threads also
// stride-zero the output buffer (fuses the old memset node).
__global__ void setup_zero_kernel(const float* __restrict__ mu_raw,
                                  const float* __restrict__ Dmu_raw,
                                  const float* __restrict__ T0mu_raw,
                                  const float* __restrict__ Ly_raw,
                                  const float* __restrict__ xo_raw,
                                  const float* __restrict__ yo_raw,
                                  float* __restrict__ wsA,
                                  float* __restrict__ wsW,
                                  float* __restrict__ wsS,
                                  float* __restrict__ wsCW,
                                  float* __restrict__ wsSW,
                                  float* __restrict__ out, int T)
{
    int id = blockIdx.x * blockDim.x + threadIdx.x;
    int gsz = gridDim.x * blockDim.x;
    for (int i = id; i < T; i += gsz) out[i] = 0.0f;
    if (id >= NMODES) return;

    const float KF   = 1.0f / 44100.0f;
    const float PI_F = (float)M_PI;
    const double om2sq = (2.0 * M_PI * 500.0) * (2.0 * M_PI * 500.0);
    const float ALPHA_F  = (float)(3.0 * M_LN10 / om2sq * (om2sq / 6.0));
    const float BETA_F   = (float)(3.0 * M_LN10 / om2sq * (1.0 - 1.0 / 6.0));
    const float MAX_OM_F = (float)(10000.0 * 2.0 * M_PI);
    const float MIN_OM_F = (float)(20.0 * 2.0 * M_PI);
    const float KK_F     = (float)((1.0 / 44100.0) * (1.0 / 44100.0));

    float mu   = (softplusf(mu_raw[0])   + 1e-4f) * 2.43f;
    float Dmu  = (softplusf(Dmu_raw[0])  + 1e-4f) * 0.002452f;
    float T0mu = (softplusf(T0mu_raw[0]) + 1e-4f) * 0.004115f;
    float Ly   = 1.1f + 2.9f * sigmoidf(Ly_raw[0]);
    float xo   = 0.245f + 0.255f * sigmoidf(xo_raw[0]);
    float yo   = __fadd_rn(__fmul_rn(0.51f, Ly),
                           __fmul_rn(__fmul_rn(0.49f, Ly), sigmoidf(yo_raw[0])));

    float mf = (float)(id / 80 + 1);
    float nf = (float)(id % 80 + 1);

    float am = __fmul_rn(__fmul_rn(mf, PI_F), 2.0f);
    float bn = __fdiv_rn(__fmul_rn(nf, PI_F), Ly);
    float g1 = __fadd_rn(__fmul_rn(am, am), __fmul_rn(bn, bn));
    float omega_sq = __fadd_rn(__fmul_rn(T0mu, g1),
                               __fmul_rn(__fmul_rn(Dmu, g1), g1));
    float omega = sqrtf(fmaxf(omega_sq, 0.0f));
    float valid = (omega <= MAX_OM_F && omega >= MIN_OM_F) ? 1.0f : 0.0f;

    float xi_pi = (float)(0.05 * M_PI);
    float yi = __fmul_rn(0.1f, Ly);
    float InW = __fmul_rn(
        cosf(__fmul_rn(__fmul_rn(xi_pi, mf), 2.0f)),
        cosf(__fdiv_rn(__fmul_rn(__fmul_rn(yi, PI_F), nf), Ly)));
    float OutW = __fmul_rn(
        cosf(__fmul_rn(__fmul_rn(__fmul_rn(xo, PI_F), mf), 2.0f)),
        cosf(__fdiv_rn(__fmul_rn(__fmul_rn(yo, PI_F), nf), Ly)));

    float sigma = __fadd_rn(ALPHA_F, __fmul_rn(BETA_F, __fmul_rn(omega, omega)));
    float ms = __fmul_rn(__fmul_rn(__fmul_rn(0.25f, mu), 0.5f), Ly);
    float P = __fmul_rn(
        __fdiv_rn(__fmul_rn(__fmul_rn(__fmul_rn(OutW, InW), KK_F),
                            expf(__fmul_rn(-sigma, KF))),
                  ms),
        valid);
    float den = __fadd_rn(sinf(__fmul_rn(omega, KF)), 1e-8f);
    float A = __fdiv_rn(P, den);

    const double Kd = 1.0 / 44100.0;
    double th = (double)omega * Kd;
    double dd = exp(-(double)sigma * Kd);
    wsA[id]  = A;
    wsW[id]  = omega;
    wsS[id]  = sigma;
    wsCW[id] = (float)(dd * cos(th));
    wsSW[id] = (float)(dd * sin(th));
}

// Thread owns 10 modes (40 state VGPRs, no spill). Per BATCH=6 samples:
// rotate+accumulate batch k while the butterfly+atomics of batch k-1 sit in
// the same straight-line body (independent -> scheduler interleaves, hiding
// shfl/ds waits under FMA issue). 818 blocks x 5 waves = 16 waves/CU.
__global__ __launch_bounds__(TB) void accum_kernel(
    const float* __restrict__ wsA,
    const float* __restrict__ wsW,
    const float* __restrict__ wsS,
    const float* __restrict__ wsCW,
    const float* __restrict__ wsSW,
    float* __restrict__ out, int T)
{
    const int tid  = threadIdx.x;
    const int t0   = blockIdx.x * TC;
    const int base = blockIdx.y * (TB * MPT);

    const float  KF     = 1.0f / 44100.0f;
    const double Kd     = 1.0 / 44100.0;
    const double TWO_PI = 6.283185307179586476925286766559;
    const double I2PI   = 0.15915494309189533576888376337251;

    float S[MPT], C[MPT], CW[MPT], SW[MPT];
    #pragma unroll
    for (int j = 0; j < MPT; ++j) {
        int m = base + j * TB + tid;
        float A  = wsA[m];
        float w  = wsW[m];
        float sg = wsS[m];
        CW[j] = wsCW[m];
        SW[j] = wsSW[m];
        // exact phase init at t0 (double range reduction), env in float
        double ph = (double)t0 * (double)w * Kd;
        double q  = rint(ph * I2PI);
        float  r  = (float)fma(-q, TWO_PI, ph);
        float s0, c0;
        __sincosf(r, &s0, &c0);
        float env = A * __expf(-sg * (float)(t0 - 1) * KF);
        S[j] = env * s0;
        C[j] = env * c0;
    }

    const int lane = tid & 63;

    float accP[BATCH];        // previous batch's per-lane partials
    #pragma unroll
    for (int b = 0; b < BATCH; ++b) accP[b] = 0.0f;

    #pragma unroll 1
    for (int it = 0; it < TC + BATCH; it += BATCH) {
        float accC[BATCH];
        // --- produce current batch (only if in range) ---
        if (it < TC) {
            #pragma unroll
            for (int b = 0; b < BATCH; ++b) {
                // per-lane sum of current S (sample t0+it+b), 2-level tree
                float s01 = S[0] + S[1], s23 = S[2] + S[3];
                float s45 = S[4] + S[5], s67 = S[6] + S[7];
                float s89 = S[8] + S[9];
                accC[b] = ((s01 + s23) + (s45 + s67)) + s89;
                // advance all phasors one step
                #pragma unroll
                for (int j = 0; j < MPT; ++j) {
                    float nS = __fmaf_rn(S[j], CW[j],  C[j] * SW[j]);
                    float nC = __fmaf_rn(C[j], CW[j], -(S[j] * SW[j]));
                    S[j] = nS;
                    C[j] = nC;
                }
            }
        }
        // --- reduce + commit PREVIOUS batch (independent of the above) ---
        if (it > 0) {
            #pragma unroll
            for (int off = 32; off > 0; off >>= 1) {
                #pragma unroll
                for (int b = 0; b < BATCH; ++b)
                    accP[b] += __shfl_xor(accP[b], off, 64);
            }
            if (lane == 0) {
                int tp = t0 + it - BATCH;
                #pragma unroll
                for (int b = 0; b < BATCH; ++b)
                    if (tp + b < T) atomicAdd(&out[tp + b], accP[b]);
            }
        }
        #pragma unroll
        for (int b = 0; b < BATCH; ++b) accP[b] = accC[b];
    }
}

// Single block: find peak |out|, then divide through.
__global__ __launch_bounds__(1024) void norm_kernel(float* __restrict__ out, int T)
{
    __shared__ float red[16];
    __shared__ float peakv;
    float mx = 0.0f;
    for (int i = threadIdx.x; i < T; i += 1024) mx = fmaxf(mx, fabsf(out[i]));
    #pragma unroll
    for (int off = 32; off > 0; off >>= 1)
        mx = fmaxf(mx, __shfl_xor(mx, off, 64));
    int lane = threadIdx.x & 63, wv = threadIdx.x >> 6;
    if (lane == 0) red[wv] = mx;
    __syncthreads();
    if (threadIdx.x == 0) {
        float m = red[0];
        #pragma unroll
        for (int i = 1; i < 16; ++i) m = fmaxf(m, red[i]);
        peakv = m + 1e-8f;
    }
    __syncthreads();
    float pk = peakv;
    for (int i = threadIdx.x; i < T; i += 1024) out[i] = __fdiv_rn(out[i], pk);
}

extern "C" void kernel_launch(void* const* d_in, const int* in_sizes, int n_in,
                              void* d_out, int out_size, void* d_ws, size_t ws_size,
                              hipStream_t stream)
{
    const float* mu   = (const float*)d_in[0];
    const float* Dmu  = (const float*)d_in[1];
    const float* T0mu = (const float*)d_in[2];
    const float* Lyr  = (const float*)d_in[3];
    const float* xor_ = (const float*)d_in[4];
    const float* yor_ = (const float*)d_in[5];
    float* out = (float*)d_out;

    float* ws   = (float*)d_ws;
    float* wsA  = ws;
    float* wsW  = ws + NMODES;
    float* wsS  = ws + 2 * NMODES;
    float* wsCW = ws + 3 * NMODES;
    float* wsSW = ws + 4 * NMODES;

    int T = out_size;
    int tchunks = (T + TC - 1) / TC;

    setup_zero_kernel<<<(NMODES + 255) / 256, 256, 0, stream>>>(
        mu, Dmu, T0mu, Lyr, xor_, yor_, wsA, wsW, wsS, wsCW, wsSW, out, T);
    accum_kernel<<<dim3(tchunks, MG), TB, 0, stream>>>(wsA, wsW, wsS, wsCW, wsSW, out, T);
    norm_kernel<<<1, 1024, 0, stream>>>(out, T);
}

// Round 8
// 102.003 us; speedup vs baseline: 1.2052x; 1.2052x over previous
//
#include <hip/hip_runtime.h>
#include <math.h>

#define NMODES 6400
#define TB     128                // 2 waves per block
#define MPT    10                 // modes per thread (5 float2 pairs)
#define NPAIR  5
#define MG     5                  // mode groups: TB*MPT*MG == NMODES
#define BATCH  6                  // samples per butterfly batch
#define TC     42                 // samples per time-chunk (22050 = 525*42)

typedef float v2f __attribute__((ext_vector_type(2)));

static __device__ __forceinline__ float softplusf(float x) {
    return log1pf(expf(-fabsf(x))) + fmaxf(x, 0.0f);
}
static __device__ __forceinline__ float sigmoidf(float x) {
    return 1.0f / (1.0f + expf(-x));
}

// ONE launch: per-mode constants + stride-zero of out.
__global__ void setup_zero_kernel(const float* __restrict__ mu_raw,
                                  const float* __restrict__ Dmu_raw,
                                  const float* __restrict__ T0mu_raw,
                                  const float* __restrict__ Ly_raw,
                                  const float* __restrict__ xo_raw,
                                  const float* __restrict__ yo_raw,
                                  float* __restrict__ wsA,
                                  float* __restrict__ wsW,
                                  float* __restrict__ wsS,
                                  float* __restrict__ wsCW,
                                  float* __restrict__ wsSW,
                                  float* __restrict__ out, int T)
{
    int id = blockIdx.x * blockDim.x + threadIdx.x;
    int gsz = gridDim.x * blockDim.x;
    for (int i = id; i < T; i += gsz) out[i] = 0.0f;
    if (id >= NMODES) return;

    const float KF   = 1.0f / 44100.0f;
    const float PI_F = (float)M_PI;
    const double om2sq = (2.0 * M_PI * 500.0) * (2.0 * M_PI * 500.0);
    const float ALPHA_F  = (float)(3.0 * M_LN10 / om2sq * (om2sq / 6.0));
    const float BETA_F   = (float)(3.0 * M_LN10 / om2sq * (1.0 - 1.0 / 6.0));
    const float MAX_OM_F = (float)(10000.0 * 2.0 * M_PI);
    const float MIN_OM_F = (float)(20.0 * 2.0 * M_PI);
    const float KK_F     = (float)((1.0 / 44100.0) * (1.0 / 44100.0));

    float mu   = (softplusf(mu_raw[0])   + 1e-4f) * 2.43f;
    float Dmu  = (softplusf(Dmu_raw[0])  + 1e-4f) * 0.002452f;
    float T0mu = (softplusf(T0mu_raw[0]) + 1e-4f) * 0.004115f;
    float Ly   = 1.1f + 2.9f * sigmoidf(Ly_raw[0]);
    float xo   = 0.245f + 0.255f * sigmoidf(xo_raw[0]);
    float yo   = __fadd_rn(__fmul_rn(0.51f, Ly),
                           __fmul_rn(__fmul_rn(0.49f, Ly), sigmoidf(yo_raw[0])));

    float mf = (float)(id / 80 + 1);
    float nf = (float)(id % 80 + 1);

    float am = __fmul_rn(__fmul_rn(mf, PI_F), 2.0f);
    float bn = __fdiv_rn(__fmul_rn(nf, PI_F), Ly);
    float g1 = __fadd_rn(__fmul_rn(am, am), __fmul_rn(bn, bn));
    float omega_sq = __fadd_rn(__fmul_rn(T0mu, g1),
                               __fmul_rn(__fmul_rn(Dmu, g1), g1));
    float omega = sqrtf(fmaxf(omega_sq, 0.0f));
    float valid = (omega <= MAX_OM_F && omega >= MIN_OM_F) ? 1.0f : 0.0f;

    float xi_pi = (float)(0.05 * M_PI);
    float yi = __fmul_rn(0.1f, Ly);
    float InW = __fmul_rn(
        cosf(__fmul_rn(__fmul_rn(xi_pi, mf), 2.0f)),
        cosf(__fdiv_rn(__fmul_rn(__fmul_rn(yi, PI_F), nf), Ly)));
    float OutW = __fmul_rn(
        cosf(__fmul_rn(__fmul_rn(__fmul_rn(xo, PI_F), mf), 2.0f)),
        cosf(__fdiv_rn(__fmul_rn(__fmul_rn(yo, PI_F), nf), Ly)));

    float sigma = __fadd_rn(ALPHA_F, __fmul_rn(BETA_F, __fmul_rn(omega, omega)));
    float ms = __fmul_rn(__fmul_rn(__fmul_rn(0.25f, mu), 0.5f), Ly);
    float P = __fmul_rn(
        __fdiv_rn(__fmul_rn(__fmul_rn(__fmul_rn(OutW, InW), KK_F),
                            expf(__fmul_rn(-sigma, KF))),
                  ms),
        valid);
    float den = __fadd_rn(sinf(__fmul_rn(omega, KF)), 1e-8f);
    float A = __fdiv_rn(P, den);

    const double Kd = 1.0 / 44100.0;
    double th = (double)omega * Kd;
    double dd = exp(-(double)sigma * Kd);
    wsA[id]  = A;
    wsW[id]  = omega;
    wsS[id]  = sigma;
    wsCW[id] = (float)(dd * cos(th));
    wsSW[id] = (float)(dd * sin(th));
}

// Thread owns 10 modes as 5 float2 pairs -> rotation & accumulation lower to
// v_pk_fma_f32 / v_pk_add_f32 (gfx950 packed fp32), halving the dominant
// instruction class. 2625 two-wave blocks (~5 waves/SIMD potential). Waves
// act independently: batch-6 butterflies + lane0 atomics, no __syncthreads.
__global__ __launch_bounds__(TB) void accum_kernel(
    const float* __restrict__ wsA,
    const float* __restrict__ wsW,
    const float* __restrict__ wsS,
    const float* __restrict__ wsCW,
    const float* __restrict__ wsSW,
    float* __restrict__ out, int T)
{
    const int tid  = threadIdx.x;
    const int t0   = blockIdx.x * TC;
    const int base = blockIdx.y * (TB * MPT);

    const float  KF     = 1.0f / 44100.0f;
    const double Kd     = 1.0 / 44100.0;
    const double TWO_PI = 6.283185307179586476925286766559;
    const double I2PI   = 0.15915494309189533576888376337251;

    v2f S[NPAIR], C[NPAIR], CW[NPAIR], SW[NPAIR];
    #pragma unroll
    for (int p = 0; p < NPAIR; ++p) {
        int m = base + p * (TB * 2) + tid * 2;     // even -> 8B aligned
        CW[p] = *(const v2f*)(wsCW + m);
        SW[p] = *(const v2f*)(wsSW + m);
        v2f A  = *(const v2f*)(wsA + m);
        v2f w  = *(const v2f*)(wsW + m);
        v2f sg = *(const v2f*)(wsS + m);
        #pragma unroll
        for (int k = 0; k < 2; ++k) {
            double ph = (double)t0 * (double)w[k] * Kd;
            double q  = rint(ph * I2PI);
            float  r  = (float)fma(-q, TWO_PI, ph);
            float s0, c0;
            __sincosf(r, &s0, &c0);
            float env = A[k] * __expf(-sg[k] * (float)(t0 - 1) * KF);
            S[p][k] = env * s0;
            C[p][k] = env * c0;
        }
    }

    const int lane = tid & 63;

    #pragma unroll 1
    for (int it = 0; it < TC; it += BATCH) {
        float acc[BATCH];
        #pragma unroll
        for (int b = 0; b < BATCH; ++b) {
            // packed per-lane sum of current S (sample t0+it+b)
            v2f s01 = S[0] + S[1];
            v2f s23 = S[2] + S[3];
            v2f sp  = (s01 + s23) + S[4];
            acc[b] = sp[0] + sp[1];
            // advance all phasors one step (packed: 4 pk-ops per pair)
            #pragma unroll
            for (int p = 0; p < NPAIR; ++p) {
                v2f nS = __builtin_elementwise_fma(S[p], CW[p], C[p] * SW[p]);
                v2f nC = __builtin_elementwise_fma(C[p], CW[p], -(S[p] * SW[p]));
                S[p] = nS;
                C[p] = nC;
            }
        }
        // BATCH independent butterflies, interleaved (shfl latencies overlap)
        #pragma unroll
        for (int off = 32; off > 0; off >>= 1) {
            #pragma unroll
            for (int b = 0; b < BATCH; ++b)
                acc[b] += __shfl_xor(acc[b], off, 64);
        }
        if (lane == 0) {
            int t = t0 + it;
            #pragma unroll
            for (int b = 0; b < BATCH; ++b)
                if (t + b < T) atomicAdd(&out[t + b], acc[b]);
        }
    }
}

// Single block: find peak |out|, then divide through.
__global__ __launch_bounds__(1024) void norm_kernel(float* __restrict__ out, int T)
{
    __shared__ float red[16];
    __shared__ float peakv;
    float mx = 0.0f;
    for (int i = threadIdx.x; i < T; i += 1024) mx = fmaxf(mx, fabsf(out[i]));
    #pragma unroll
    for (int off = 32; off > 0; off >>= 1)
        mx = fmaxf(mx, __shfl_xor(mx, off, 64));
    int lane = threadIdx.x & 63, wv = threadIdx.x >> 6;
    if (lane == 0) red[wv] = mx;
    __syncthreads();
    if (threadIdx.x == 0) {
        float m = red[0];
        #pragma unroll
        for (int i = 1; i < 16; ++i) m = fmaxf(m, red[i]);
        peakv = m + 1e-8f;
    }
    __syncthreads();
    float pk = peakv;
    for (int i = threadIdx.x; i < T; i += 1024) out[i] = __fdiv_rn(out[i], pk);
}

extern "C" void kernel_launch(void* const* d_in, const int* in_sizes, int n_in,
                              void* d_out, int out_size, void* d_ws, size_t ws_size,
                              hipStream_t stream)
{
    const float* mu   = (const float*)d_in[0];
    const float* Dmu  = (const float*)d_in[1];
    const float* T0mu = (const float*)d_in[2];
    const float* Lyr  = (const float*)d_in[3];
    const float* xor_ = (const float*)d_in[4];
    const float* yor_ = (const float*)d_in[5];
    float* out = (float*)d_out;

    float* ws   = (float*)d_ws;
    float* wsA  = ws;
    float* wsW  = ws + NMODES;
    float* wsS  = ws + 2 * NMODES;
    float* wsCW = ws + 3 * NMODES;
    float* wsSW = ws + 4 * NMODES;

    int T = out_size;
    int tchunks = (T + TC - 1) / TC;

    setup_zero_kernel<<<(NMODES + 255) / 256, 256, 0, stream>>>(
        mu, Dmu, T0mu, Lyr, xor_, yor_, wsA, wsW, wsS, wsCW, wsSW, out, T);
    accum_kernel<<<dim3(tchunks, MG), TB, 0, stream>>>(wsA, wsW, wsS, wsCW, wsSW, out, T);
    norm_kernel<<<1, 1024, 0, stream>>>(out, T);
}